// Round 1
// baseline (186.784 us; speedup 1.0000x reference)
//
#include <hip/hip_runtime.h>
#include <cstdint>
#include <cstddef>

using short8 = __attribute__((ext_vector_type(8))) short;   // 8 bf16 (4 VGPRs)
using f32x4  = __attribute__((ext_vector_type(4))) float;   // MFMA C/D

#define DEV static __device__ __forceinline__

constexpr int Bn = 4, Cn = 256, Ln = 2048, Hn = 8, Dn = 64, HIDn = 512;

DEV unsigned short f2bf(float f){            // fp32 -> bf16 bits, round-nearest-even
  union { float f; uint32_t u; } v; v.f = f;
  uint32_t u = v.u;
  return (unsigned short)((u + 0x7FFFu + ((u >> 16) & 1u)) >> 16);
}

// ---------------- f32 -> bf16 weight convert ----------------
__global__ __launch_bounds__(256) void k_cvt(const float* __restrict__ in,
                                             unsigned short* __restrict__ out, int n){
  int i = blockIdx.x * 256 + threadIdx.x;
  int stride = gridDim.x * 256;
  for (; i < n; i += stride) out[i] = f2bf(in[i]);
}

// ---------------- column norms: s[b*Ln+l] = sqrt(Cn)/max(||x[:,l]||, eps) ----------------
// grid 128 blocks x 256: block handles 64 l-columns; wave w sums c in [w*64, w*64+64)
__global__ __launch_bounds__(256) void k_colnorm(const float* __restrict__ x,
                                                 float* __restrict__ s){
  __shared__ float ps[4][64];
  int gcol = blockIdx.x * 64;             // 0..8191 in steps of 64
  int b = gcol >> 11;
  int l = (gcol & 2047) + (threadIdx.x & 63);
  int w = threadIdx.x >> 6;
  const float* xp = x + ((size_t)b * Cn + w * 64) * Ln + l;
  float acc = 0.f;
  #pragma unroll 8
  for (int cc = 0; cc < 64; ++cc){ float v = xp[(size_t)cc * Ln]; acc += v * v; }
  ps[w][threadIdx.x & 63] = acc;
  __syncthreads();
  if (threadIdx.x < 64){
    float t = ps[0][threadIdx.x] + ps[1][threadIdx.x] + ps[2][threadIdx.x] + ps[3][threadIdx.x];
    s[gcol + threadIdx.x] = 16.0f / fmaxf(sqrtf(t), 1e-12f);
  }
}

// ---------------- transpose + scale + g1 + bf16: xT[(b*Ln+l)*Cn + c] ----------------
// grid (32, 4, 4) = (l-tiles, c-tiles, b); block 256
__global__ __launch_bounds__(256) void k_xt(const float* __restrict__ x,
                                            const float* __restrict__ s,
                                            const float* __restrict__ g1,
                                            unsigned short* __restrict__ xT){
  __shared__ float xs[64][65];
  int b  = blockIdx.z;
  int c0 = blockIdx.y * 64;
  int l0 = blockIdx.x * 64;
  int t  = threadIdx.x;
  int i = t >> 6, j = t & 63;
  const float* xp = x + ((size_t)b * Cn + c0) * Ln + l0;
  #pragma unroll
  for (int it = 0; it < 16; ++it)
    xs[i + it * 4][j] = xp[(size_t)(i + it * 4) * Ln + j];
  __syncthreads();
  int jj = t >> 2, part = t & 3;
  float sc = s[b * Ln + l0 + jj];
  unsigned short* op = xT + ((size_t)(b * Ln + l0 + jj)) * Cn + c0 + part * 16;
  #pragma unroll
  for (int hb = 0; hb < 2; ++hb){
    short8 pack;
    #pragma unroll
    for (int m = 0; m < 8; ++m){
      int c = part * 16 + hb * 8 + m;
      pack[m] = (short)f2bf(xs[c][jj] * sc * g1[c0 + c]);
    }
    *reinterpret_cast<short8*>(op + hb * 8) = pack;
  }
}

// ---------------- QK GEMM, D[l][o] orientation -> q,k in (b,h,l,d) bf16 ----------------
// grid (16, 16, 4): (l/128, 1024/64, b); block 256 = 4 waves (2x2), wave tile 64x32
__global__ __launch_bounds__(256) void k_gemm_qk(const unsigned short* __restrict__ xT,
                                                 const unsigned short* __restrict__ w,
                                                 unsigned short* __restrict__ qb,
                                                 unsigned short* __restrict__ kb){
  int b  = blockIdx.z;
  int l0 = blockIdx.x * 128;
  int n0 = blockIdx.y * 64;
  int wv = threadIdx.x >> 6, lane = threadIdx.x & 63;
  int grp = lane >> 4, lc = lane & 15;
  int lw = l0 + (wv >> 1) * 64;
  int nw = n0 + (wv & 1) * 32;
  f32x4 acc[4][2] = {};
  const unsigned short* xb = xT + (size_t)b * Ln * Cn;
  for (int k0 = 0; k0 < Cn; k0 += 32){
    int kc = k0 + grp * 8;
    short8 afr[4], bfr[2];
    #pragma unroll
    for (int mt = 0; mt < 4; ++mt)
      afr[mt] = *reinterpret_cast<const short8*>(xb + (size_t)(lw + mt * 16 + lc) * Cn + kc);
    #pragma unroll
    for (int nt = 0; nt < 2; ++nt)
      bfr[nt] = *reinterpret_cast<const short8*>(w + (size_t)(nw + nt * 16 + lc) * Cn + kc);
    #pragma unroll
    for (int mt = 0; mt < 4; ++mt)
      #pragma unroll
      for (int nt = 0; nt < 2; ++nt)
        acc[mt][nt] = __builtin_amdgcn_mfma_f32_16x16x32_bf16(afr[mt], bfr[nt], acc[mt][nt], 0, 0, 0);
  }
  #pragma unroll
  for (int mt = 0; mt < 4; ++mt)
    #pragma unroll
    for (int nt = 0; nt < 2; ++nt)
      #pragma unroll
      for (int r = 0; r < 4; ++r){
        int l = lw + mt * 16 + grp * 4 + r;
        int o = nw + nt * 16 + lc;
        float v = acc[mt][nt][r];
        if (o < HIDn){
          size_t idx = (((size_t)(b * Hn + (o >> 6)) * Ln + l) << 6) | (size_t)(o & 63);
          qb[idx] = f2bf(v * 0.125f);         // fold dim_head^-0.5
        } else {
          int o2 = o - HIDn;
          size_t idx = (((size_t)(b * Hn + (o2 >> 6)) * Ln + l) << 6) | (size_t)(o2 & 63);
          kb[idx] = f2bf(v);
        }
      }
}

// ---------------- V GEMM, D[o][l] orientation -> v in (b, 512, l) bf16 ----------------
// grid (16, 8, 4): (l/128, 512/64, b); block 256 = 4 waves (2x2), wave tile 32x64
__global__ __launch_bounds__(256) void k_gemm_v(const unsigned short* __restrict__ xT,
                                                const unsigned short* __restrict__ w,
                                                unsigned short* __restrict__ vb){
  int b  = blockIdx.z;
  int m0 = blockIdx.y * 64;
  int l0 = blockIdx.x * 128;
  int wv = threadIdx.x >> 6, lane = threadIdx.x & 63;
  int grp = lane >> 4, lc = lane & 15;
  int mw = m0 + (wv >> 1) * 32;
  int lw = l0 + (wv & 1) * 64;
  f32x4 acc[2][4] = {};
  const unsigned short* xb = xT + (size_t)b * Ln * Cn;
  const unsigned short* wvp = w + (size_t)1024 * Cn;     // v rows of w_qkv
  for (int k0 = 0; k0 < Cn; k0 += 32){
    int kc = k0 + grp * 8;
    short8 afr[2], bfr[4];
    #pragma unroll
    for (int mt = 0; mt < 2; ++mt)
      afr[mt] = *reinterpret_cast<const short8*>(wvp + (size_t)(mw + mt * 16 + lc) * Cn + kc);
    #pragma unroll
    for (int nt = 0; nt < 4; ++nt)
      bfr[nt] = *reinterpret_cast<const short8*>(xb + (size_t)(lw + nt * 16 + lc) * Cn + kc);
    #pragma unroll
    for (int mt = 0; mt < 2; ++mt)
      #pragma unroll
      for (int nt = 0; nt < 4; ++nt)
        acc[mt][nt] = __builtin_amdgcn_mfma_f32_16x16x32_bf16(afr[mt], bfr[nt], acc[mt][nt], 0, 0, 0);
  }
  #pragma unroll
  for (int mt = 0; mt < 2; ++mt)
    #pragma unroll
    for (int nt = 0; nt < 4; ++nt)
      #pragma unroll
      for (int r = 0; r < 4; ++r){
        int o = mw + mt * 16 + grp * 4 + r;
        int l = lw + nt * 16 + lc;
        vb[((size_t)(b * HIDn + o)) * Ln + l] = f2bf(acc[mt][nt][r]);
      }
}

// ---------------- flash attention ----------------
// grid (32, 32): (q-tiles of 64, b*h); block 256 = 4 waves, wave owns 16 q-rows
__global__ __launch_bounds__(256) void k_attn(const unsigned short* __restrict__ qb,
                                              const unsigned short* __restrict__ kb,
                                              const unsigned short* __restrict__ vb,
                                              unsigned short* __restrict__ yb){
  int qt = blockIdx.x;
  int bh = blockIdx.y;
  int b = bh >> 3, h = bh & 7;
  int tid = threadIdx.x;
  int wv = tid >> 6, lane = tid & 63;
  int grp = lane >> 4, lc = lane & 15;
  const unsigned short* qp = qb + (size_t)bh * Ln * Dn;
  const unsigned short* kp = kb + (size_t)bh * Ln * Dn;
  const unsigned short* vp = vb + ((size_t)(b * HIDn + h * Dn)) * Ln;
  unsigned short* yp = yb + ((size_t)b * Ln) * HIDn + h * Dn;

  __shared__ alignas(16) unsigned short Klds[4096];   // [64 j][64 d] bf16, XOR-swizzled rows
  __shared__ alignas(16) unsigned short Vlds[4096];   // [64 dd][64 j]
  __shared__ alignas(16) unsigned short Plds[4096];   // 4 waves x [16 i][64 j]
  char* Kb = (char*)Klds; char* Vb = (char*)Vlds;
  char* Pb = (char*)Plds + wv * 2048;

  int qrow0 = qt * 64 + wv * 16;
  short8 qfr[2];
  #pragma unroll
  for (int kk = 0; kk < 2; ++kk)
    qfr[kk] = *reinterpret_cast<const short8*>(qp + (size_t)(qrow0 + lc) * Dn + kk * 32 + grp * 8);

  f32x4 accy[4] = {};
  float mrow[4] = {-1e30f, -1e30f, -1e30f, -1e30f};
  float ssum[4] = {0.f, 0.f, 0.f, 0.f};

  for (int kt = 0; kt < Ln / 64; ++kt){
    int j0 = kt * 64;
    __syncthreads();                                   // protect LDS overwrite
    #pragma unroll
    for (int it = 0; it < 2; ++it){                    // stage K,V: 512 x 16B chunks each
      int chunk = tid + it * 256;
      int row = chunk >> 3, c16 = chunk & 7;
      int dst = row * 128 + ((c16 * 16) ^ ((row & 7) << 4));
      *reinterpret_cast<short8*>(Kb + dst) =
        *reinterpret_cast<const short8*>(kp + (size_t)(j0 + row) * Dn + c16 * 8);
      *reinterpret_cast<short8*>(Vb + dst) =
        *reinterpret_cast<const short8*>(vp + (size_t)row * Ln + j0 + c16 * 8);
    }
    __syncthreads();

    // S = Q K^T  (16 q-rows x 64 keys per wave)
    f32x4 sacc[4];
    #pragma unroll
    for (int jt = 0; jt < 4; ++jt){
      int row = jt * 16 + lc;
      int sw = (row & 7) << 4;
      short8 kf0 = *reinterpret_cast<const short8*>(Kb + row * 128 + ((grp * 16) ^ sw));
      short8 kf1 = *reinterpret_cast<const short8*>(Kb + row * 128 + ((64 + grp * 16) ^ sw));
      f32x4 z = {0.f, 0.f, 0.f, 0.f};
      z = __builtin_amdgcn_mfma_f32_16x16x32_bf16(qfr[0], kf0, z, 0, 0, 0);
      z = __builtin_amdgcn_mfma_f32_16x16x32_bf16(qfr[1], kf1, z, 0, 0, 0);
      sacc[jt] = z;
    }

    // online softmax; lane holds S[grp*4+r][jt*16+lc]
    float pj[4][4];
    #pragma unroll
    for (int r = 0; r < 4; ++r){
      float m = fmaxf(fmaxf(sacc[0][r], sacc[1][r]), fmaxf(sacc[2][r], sacc[3][r]));
      #pragma unroll
      for (int sh = 1; sh < 16; sh <<= 1) m = fmaxf(m, __shfl_xor(m, sh, 64));
      float mnew = fmaxf(mrow[r], m);
      float sum = 0.f;
      #pragma unroll
      for (int jt = 0; jt < 4; ++jt){
        float p = __expf(sacc[jt][r] - mnew);
        pj[jt][r] = p; sum += p;
      }
      #pragma unroll
      for (int sh = 1; sh < 16; sh <<= 1) sum += __shfl_xor(sum, sh, 64);
      float corr = __expf(mrow[r] - mnew);
      ssum[r] = ssum[r] * corr + sum;
      mrow[r] = mnew;
      #pragma unroll
      for (int ddt = 0; ddt < 4; ++ddt) accy[ddt][r] *= corr;
    }

    // P: D-layout -> A-layout via per-wave swizzled LDS
    #pragma unroll
    for (int jt = 0; jt < 4; ++jt)
      #pragma unroll
      for (int r = 0; r < 4; ++r){
        int row = grp * 4 + r;
        *reinterpret_cast<unsigned short*>(Pb + row * 128 + ((jt * 32 + lc * 2) ^ ((row & 7) << 4))) =
          f2bf(pj[jt][r]);
      }
    short8 pfr[2];
    #pragma unroll
    for (int kk = 0; kk < 2; ++kk)
      pfr[kk] = *reinterpret_cast<const short8*>(Pb + lc * 128 + ((kk * 64 + grp * 16) ^ ((lc & 7) << 4)));

    // y += P V^T
    #pragma unroll
    for (int ddt = 0; ddt < 4; ++ddt){
      int row = ddt * 16 + lc;
      int sw = (row & 7) << 4;
      short8 vf0 = *reinterpret_cast<const short8*>(Vb + row * 128 + ((grp * 16) ^ sw));
      short8 vf1 = *reinterpret_cast<const short8*>(Vb + row * 128 + ((64 + grp * 16) ^ sw));
      accy[ddt] = __builtin_amdgcn_mfma_f32_16x16x32_bf16(pfr[0], vf0, accy[ddt], 0, 0, 0);
      accy[ddt] = __builtin_amdgcn_mfma_f32_16x16x32_bf16(pfr[1], vf1, accy[ddt], 0, 0, 0);
    }
  }

  #pragma unroll
  for (int ddt = 0; ddt < 4; ++ddt)
    #pragma unroll
    for (int r = 0; r < 4; ++r){
      int l = qrow0 + grp * 4 + r;
      yp[(size_t)l * HIDn + ddt * 16 + lc] = f2bf(accy[ddt][r] / ssum[r]);
    }
}

// ---------------- out GEMM (M=256 full) + bias + fused RMSNorm + g2 ----------------
// grid (64, 4): (l/32, b); block 256 = 4 waves, wave: 64 o-rows x 32 l-cols
__global__ __launch_bounds__(256) void k_out(const unsigned short* __restrict__ yb,
                                             const unsigned short* __restrict__ w,
                                             const float* __restrict__ bias,
                                             const float* __restrict__ g2,
                                             float* __restrict__ out){
  int b  = blockIdx.y;
  int l0 = blockIdx.x * 32;
  int wv = threadIdx.x >> 6, lane = threadIdx.x & 63;
  int grp = lane >> 4, lc = lane & 15;
  int mw = wv * 64;
  f32x4 acc[4][2] = {};
  const unsigned short* ybp = yb + (size_t)b * Ln * HIDn + (size_t)l0 * HIDn;
  for (int k0 = 0; k0 < HIDn; k0 += 32){
    int kc = k0 + grp * 8;
    short8 afr[4], bfr[2];
    #pragma unroll
    for (int mt = 0; mt < 4; ++mt)
      afr[mt] = *reinterpret_cast<const short8*>(w + (size_t)(mw + mt * 16 + lc) * HIDn + kc);
    #pragma unroll
    for (int nt = 0; nt < 2; ++nt)
      bfr[nt] = *reinterpret_cast<const short8*>(ybp + (size_t)(nt * 16 + lc) * HIDn + kc);
    #pragma unroll
    for (int mt = 0; mt < 4; ++mt)
      #pragma unroll
      for (int nt = 0; nt < 2; ++nt)
        acc[mt][nt] = __builtin_amdgcn_mfma_f32_16x16x32_bf16(afr[mt], bfr[nt], acc[mt][nt], 0, 0, 0);
  }
  __shared__ float cs[4][32];
  __shared__ float sc2[32];
  float part[2] = {0.f, 0.f};
  #pragma unroll
  for (int mt = 0; mt < 4; ++mt)
    #pragma unroll
    for (int nt = 0; nt < 2; ++nt)
      #pragma unroll
      for (int r = 0; r < 4; ++r){
        int o = mw + mt * 16 + grp * 4 + r;
        float v = acc[mt][nt][r] + bias[o];
        acc[mt][nt][r] = v;
        part[nt] += v * v;
      }
  #pragma unroll
  for (int nt = 0; nt < 2; ++nt)
    #pragma unroll
    for (int sh = 16; sh < 64; sh <<= 1) part[nt] += __shfl_xor(part[nt], sh, 64);
  if (lane < 16){ cs[wv][lc] = part[0]; cs[wv][16 + lc] = part[1]; }
  __syncthreads();
  if (threadIdx.x < 32){
    float t = cs[0][threadIdx.x] + cs[1][threadIdx.x] + cs[2][threadIdx.x] + cs[3][threadIdx.x];
    sc2[threadIdx.x] = 16.0f / fmaxf(sqrtf(t), 1e-12f);
  }
  __syncthreads();
  #pragma unroll
  for (int nt = 0; nt < 2; ++nt){
    float s2 = sc2[nt * 16 + lc];
    #pragma unroll
    for (int mt = 0; mt < 4; ++mt)
      #pragma unroll
      for (int r = 0; r < 4; ++r){
        int o = mw + mt * 16 + grp * 4 + r;
        int l = l0 + nt * 16 + lc;
        out[((size_t)(b * Cn + o)) * Ln + l] = acc[mt][nt][r] * s2 * g2[o];
      }
  }
}

// ---------------- launch ----------------
extern "C" void kernel_launch(void* const* d_in, const int* in_sizes, int n_in,
                              void* d_out, int out_size, void* d_ws, size_t ws_size,
                              hipStream_t stream){
  const float* x     = (const float*)d_in[0];
  const float* g1    = (const float*)d_in[1];
  const float* w_qkv = (const float*)d_in[2];
  const float* w_out = (const float*)d_in[3];
  const float* b_out = (const float*)d_in[4];
  const float* g2    = (const float*)d_in[5];

  char* wsb = (char*)d_ws;
  unsigned short* wqkv_b = (unsigned short*)(wsb + 0);         //  786,432 B
  unsigned short* wout_b = (unsigned short*)(wsb + 786432);    //  262,144 B
  float*          sbuf   = (float*)        (wsb + 1048576);    //   32,768 B
  unsigned short* xT     = (unsigned short*)(wsb + 1081344);   // 4,194,304 B
  unsigned short* qbuf   = (unsigned short*)(wsb + 5275648);   // 8,388,608 B
  unsigned short* kbuf   = (unsigned short*)(wsb + 13664256);  // 8,388,608 B
  unsigned short* vbuf   = (unsigned short*)(wsb + 22052864);  // 8,388,608 B
  unsigned short* ybuf   = (unsigned short*)(wsb + 30441472);  // 8,388,608 B  (total ~38.8 MB)

  k_cvt<<<384, 256, 0, stream>>>(w_qkv, wqkv_b, 1536 * 256);
  k_cvt<<<128, 256, 0, stream>>>(w_out, wout_b, 256 * 512);
  k_colnorm<<<128, 256, 0, stream>>>(x, sbuf);
  k_xt<<<dim3(32, 4, 4), 256, 0, stream>>>(x, sbuf, g1, xT);
  k_gemm_qk<<<dim3(16, 16, 4), 256, 0, stream>>>(xT, wqkv_b, qbuf, kbuf);
  k_gemm_v<<<dim3(16, 8, 4), 256, 0, stream>>>(xT, wqkv_b, vbuf);
  k_attn<<<dim3(32, 32), 256, 0, stream>>>(qbuf, kbuf, vbuf, ybuf);
  k_out<<<dim3(64, 4), 256, 0, stream>>>(ybuf, wout_b, b_out, g2, (float*)d_out);
}

// Round 2
// 152.641 us; speedup vs baseline: 1.2237x; 1.2237x over previous
//
#include <hip/hip_runtime.h>
#include <cstdint>
#include <cstddef>

using short8 = __attribute__((ext_vector_type(8))) short;   // 8 bf16 (4 VGPRs)
using f32x4  = __attribute__((ext_vector_type(4))) float;   // MFMA C/D 16x16
using f32x16 = __attribute__((ext_vector_type(16))) float;  // MFMA C/D 32x32
using u32x4  = __attribute__((ext_vector_type(4))) unsigned int;

#define DEV static __device__ __forceinline__

constexpr int Bn = 4, Cn = 256, Ln = 2048, Hn = 8, Dn = 64, HIDn = 512;

DEV unsigned short f2bf(float f){            // fp32 -> bf16 bits, round-nearest-even
  union { float f; uint32_t u; } v; v.f = f;
  uint32_t u = v.u;
  return (unsigned short)((u + 0x7FFFu + ((u >> 16) & 1u)) >> 16);
}

DEV uint32_t cvtpk(float lo, float hi){      // pack 2 f32 -> 2 bf16 (lo -> bits[15:0])
  uint32_t r;
  asm("v_cvt_pk_bf16_f32 %0, %1, %2" : "=v"(r) : "v"(lo), "v"(hi));
  return r;
}

// ---------------- f32 -> bf16 weight convert ----------------
__global__ __launch_bounds__(256) void k_cvt(const float* __restrict__ in,
                                             unsigned short* __restrict__ out, int n){
  int i = blockIdx.x * 256 + threadIdx.x;
  int stride = gridDim.x * 256;
  for (; i < n; i += stride) out[i] = f2bf(in[i]);
}

// ---------------- column norms: s[b*Ln+l] = sqrt(Cn)/max(||x[:,l]||, eps) ----------------
__global__ __launch_bounds__(256) void k_colnorm(const float* __restrict__ x,
                                                 float* __restrict__ s){
  __shared__ float ps[4][64];
  int gcol = blockIdx.x * 64;
  int b = gcol >> 11;
  int l = (gcol & 2047) + (threadIdx.x & 63);
  int w = threadIdx.x >> 6;
  const float* xp = x + ((size_t)b * Cn + w * 64) * Ln + l;
  float acc = 0.f;
  #pragma unroll 8
  for (int cc = 0; cc < 64; ++cc){ float v = xp[(size_t)cc * Ln]; acc += v * v; }
  ps[w][threadIdx.x & 63] = acc;
  __syncthreads();
  if (threadIdx.x < 64){
    float t = ps[0][threadIdx.x] + ps[1][threadIdx.x] + ps[2][threadIdx.x] + ps[3][threadIdx.x];
    s[gcol + threadIdx.x] = 16.0f / fmaxf(sqrtf(t), 1e-12f);
  }
}

// ---------------- transpose + scale + g1 + bf16: xT[(b*Ln+l)*Cn + c] ----------------
__global__ __launch_bounds__(256) void k_xt(const float* __restrict__ x,
                                            const float* __restrict__ s,
                                            const float* __restrict__ g1,
                                            unsigned short* __restrict__ xT){
  __shared__ float xs[64][65];
  int b  = blockIdx.z;
  int c0 = blockIdx.y * 64;
  int l0 = blockIdx.x * 64;
  int t  = threadIdx.x;
  int i = t >> 6, j = t & 63;
  const float* xp = x + ((size_t)b * Cn + c0) * Ln + l0;
  #pragma unroll
  for (int it = 0; it < 16; ++it)
    xs[i + it * 4][j] = xp[(size_t)(i + it * 4) * Ln + j];
  __syncthreads();
  int jj = t >> 2, part = t & 3;
  float sc = s[b * Ln + l0 + jj];
  unsigned short* op = xT + ((size_t)(b * Ln + l0 + jj)) * Cn + c0 + part * 16;
  #pragma unroll
  for (int hb = 0; hb < 2; ++hb){
    short8 pack;
    #pragma unroll
    for (int m = 0; m < 8; ++m){
      int c = part * 16 + hb * 8 + m;
      pack[m] = (short)f2bf(xs[c][jj] * sc * g1[c0 + c]);
    }
    *reinterpret_cast<short8*>(op + hb * 8) = pack;
  }
}

// ---------------- QK GEMM, D[l][o] orientation -> q,k in (b,h,l,d) bf16 ----------------
__global__ __launch_bounds__(256) void k_gemm_qk(const unsigned short* __restrict__ xT,
                                                 const unsigned short* __restrict__ w,
                                                 unsigned short* __restrict__ qb,
                                                 unsigned short* __restrict__ kb){
  int b  = blockIdx.z;
  int l0 = blockIdx.x * 128;
  int n0 = blockIdx.y * 64;
  int wv = threadIdx.x >> 6, lane = threadIdx.x & 63;
  int grp = lane >> 4, lc = lane & 15;
  int lw = l0 + (wv >> 1) * 64;
  int nw = n0 + (wv & 1) * 32;
  f32x4 acc[4][2] = {};
  const unsigned short* xb = xT + (size_t)b * Ln * Cn;
  for (int k0 = 0; k0 < Cn; k0 += 32){
    int kc = k0 + grp * 8;
    short8 afr[4], bfr[2];
    #pragma unroll
    for (int mt = 0; mt < 4; ++mt)
      afr[mt] = *reinterpret_cast<const short8*>(xb + (size_t)(lw + mt * 16 + lc) * Cn + kc);
    #pragma unroll
    for (int nt = 0; nt < 2; ++nt)
      bfr[nt] = *reinterpret_cast<const short8*>(w + (size_t)(nw + nt * 16 + lc) * Cn + kc);
    #pragma unroll
    for (int mt = 0; mt < 4; ++mt)
      #pragma unroll
      for (int nt = 0; nt < 2; ++nt)
        acc[mt][nt] = __builtin_amdgcn_mfma_f32_16x16x32_bf16(afr[mt], bfr[nt], acc[mt][nt], 0, 0, 0);
  }
  // q scale folds dim_head^-0.5 AND log2(e) (attn softmax runs in exp2 domain)
  const float QSCALE = 0.125f * 1.4426950408889634f;
  #pragma unroll
  for (int mt = 0; mt < 4; ++mt)
    #pragma unroll
    for (int nt = 0; nt < 2; ++nt)
      #pragma unroll
      for (int r = 0; r < 4; ++r){
        int l = lw + mt * 16 + grp * 4 + r;
        int o = nw + nt * 16 + lc;
        float v = acc[mt][nt][r];
        if (o < HIDn){
          size_t idx = (((size_t)(b * Hn + (o >> 6)) * Ln + l) << 6) | (size_t)(o & 63);
          qb[idx] = f2bf(v * QSCALE);
        } else {
          int o2 = o - HIDn;
          size_t idx = (((size_t)(b * Hn + (o2 >> 6)) * Ln + l) << 6) | (size_t)(o2 & 63);
          kb[idx] = f2bf(v);
        }
      }
}

// ---------------- V GEMM, D[o][l] orientation -> v in (b, 512, l) bf16 ----------------
__global__ __launch_bounds__(256) void k_gemm_v(const unsigned short* __restrict__ xT,
                                                const unsigned short* __restrict__ w,
                                                unsigned short* __restrict__ vb){
  int b  = blockIdx.z;
  int m0 = blockIdx.y * 64;
  int l0 = blockIdx.x * 128;
  int wv = threadIdx.x >> 6, lane = threadIdx.x & 63;
  int grp = lane >> 4, lc = lane & 15;
  int mw = m0 + (wv >> 1) * 32;
  int lw = l0 + (wv & 1) * 64;
  f32x4 acc[2][4] = {};
  const unsigned short* xb = xT + (size_t)b * Ln * Cn;
  const unsigned short* wvp = w + (size_t)1024 * Cn;
  for (int k0 = 0; k0 < Cn; k0 += 32){
    int kc = k0 + grp * 8;
    short8 afr[2], bfr[4];
    #pragma unroll
    for (int mt = 0; mt < 2; ++mt)
      afr[mt] = *reinterpret_cast<const short8*>(wvp + (size_t)(mw + mt * 16 + lc) * Cn + kc);
    #pragma unroll
    for (int nt = 0; nt < 4; ++nt)
      bfr[nt] = *reinterpret_cast<const short8*>(xb + (size_t)(lw + nt * 16 + lc) * Cn + kc);
    #pragma unroll
    for (int mt = 0; mt < 2; ++mt)
      #pragma unroll
      for (int nt = 0; nt < 4; ++nt)
        acc[mt][nt] = __builtin_amdgcn_mfma_f32_16x16x32_bf16(afr[mt], bfr[nt], acc[mt][nt], 0, 0, 0);
  }
  #pragma unroll
  for (int mt = 0; mt < 2; ++mt)
    #pragma unroll
    for (int nt = 0; nt < 4; ++nt)
      #pragma unroll
      for (int r = 0; r < 4; ++r){
        int o = mw + mt * 16 + grp * 4 + r;
        int l = lw + nt * 16 + lc;
        vb[((size_t)(b * HIDn + o)) * Ln + l] = f2bf(acc[mt][nt][r]);
      }
}

// ---------------- flash attention, swapped-operand 32x32 structure ----------------
// 512 blocks (XCD-swizzled) x 256 threads = 4 warps; warp owns 32 q-rows; KVBLK=64.
// S^T = mfma(K, Q): lane's q = lane&31 -> lane-local softmax (1 cross-lane shfl).
// O^T = mfma(V^T, P^T): rescale also lane-local. P redistributed in-register
// via v_cvt_pk_bf16_f32 + shfl_xor(32) + select (no LDS roundtrip).
__global__ __launch_bounds__(256) void k_attn(const unsigned short* __restrict__ qb,
                                              const unsigned short* __restrict__ kb,
                                              const unsigned short* __restrict__ vb,
                                              unsigned short* __restrict__ yb){
  // XCD-aware swizzle: 512 blocks, 8 XCDs -> XCD x owns work [64x, 64x+64) = 4 bh each
  int wid = (blockIdx.x & 7) * 64 + (blockIdx.x >> 3);
  int qt = wid & 15;
  int bh = wid >> 4;
  int b = bh >> 3, h = bh & 7;
  int tid = threadIdx.x;
  int wv = tid >> 6, lane = tid & 63;
  int ln = lane & 31, hi = lane >> 5;

  const unsigned short* qp = qb + (size_t)bh * Ln * Dn;
  const unsigned short* kp = kb + (size_t)bh * Ln * Dn;
  const unsigned short* vp = vb + ((size_t)(b * HIDn + h * Dn)) * Ln;
  unsigned short* yp = yb + (size_t)b * Ln * HIDn + h * Dn;

  __shared__ alignas(16) unsigned short KV[2][2][4096];   // [buf][K|V][64 rows x 64 elems], XOR-swizzled

  // staging: 256 threads x (2 K-chunks + 2 V-chunks) x 16B per tile
  int c1 = tid + 256;
  int r0 = tid >> 3, col0 = tid & 7;
  int r1 = c1 >> 3,  col1 = c1 & 7;
  int sd0 = r0 * 128 + ((col0 * 16) ^ ((r0 & 7) << 4));
  int sd1 = r1 * 128 + ((col1 * 16) ^ ((r1 & 7) << 4));
  size_t ko0 = (size_t)r0 * Dn + col0 * 8, ko1 = (size_t)r1 * Dn + col1 * 8;
  size_t vo0 = (size_t)r0 * Ln + col0 * 8, vo1 = (size_t)r1 * Ln + col1 * 8;

  int q = qt * 128 + wv * 32 + ln;
  short8 qfr[4];
  #pragma unroll
  for (int s = 0; s < 4; ++s)
    qfr[s] = *reinterpret_cast<const short8*>(qp + (size_t)q * Dn + s * 16 + hi * 8);

  f32x16 accO[2] = {};
  float m = -1e30f, lsum = 0.f;

  // prologue: tile 0 -> LDS buf0; tile 1 loads in flight
  short8 kst0, kst1, vst0, vst1;
  kst0 = *reinterpret_cast<const short8*>(kp + ko0);
  kst1 = *reinterpret_cast<const short8*>(kp + ko1);
  vst0 = *reinterpret_cast<const short8*>(vp + vo0);
  vst1 = *reinterpret_cast<const short8*>(vp + vo1);
  {
    char* K0 = (char*)&KV[0][0][0]; char* V0 = (char*)&KV[0][1][0];
    *reinterpret_cast<short8*>(K0 + sd0) = kst0;
    *reinterpret_cast<short8*>(K0 + sd1) = kst1;
    *reinterpret_cast<short8*>(V0 + sd0) = vst0;
    *reinterpret_cast<short8*>(V0 + sd1) = vst1;
  }
  kst0 = *reinterpret_cast<const short8*>(kp + (size_t)64 * Dn + ko0);
  kst1 = *reinterpret_cast<const short8*>(kp + (size_t)64 * Dn + ko1);
  vst0 = *reinterpret_cast<const short8*>(vp + 64 + vo0);
  vst1 = *reinterpret_cast<const short8*>(vp + 64 + vo1);
  __syncthreads();

  for (int t = 0; t < 32; ++t){
    char* Kc = (char*)&KV[t & 1][0][0];
    char* Vc = (char*)&KV[t & 1][1][0];

    // ---- S^T = K Q^T : sacc[kb2] covers keys j = kb2*32 + crow(reg,hi), col q = ln
    f32x16 sacc[2] = {};
    __builtin_amdgcn_s_setprio(1);
    #pragma unroll
    for (int kb2 = 0; kb2 < 2; ++kb2){
      int row = kb2 * 32 + ln;
      int sw = (row & 7) << 4;
      #pragma unroll
      for (int s = 0; s < 4; ++s){
        short8 kf = *reinterpret_cast<const short8*>(Kc + row * 128 + ((s * 32 + hi * 16) ^ sw));
        sacc[kb2] = __builtin_amdgcn_mfma_f32_32x32x16_bf16(kf, qfr[s], sacc[kb2], 0, 0, 0);
      }
    }
    __builtin_amdgcn_s_setprio(0);

    // ---- online softmax (lane-local; one cross-pair shfl for max & sum)
    float v0[16];
    #pragma unroll
    for (int r = 0; r < 16; ++r) v0[r] = fmaxf(sacc[0][r], sacc[1][r]);
    #pragma unroll
    for (int st = 8; st >= 1; st >>= 1)
      #pragma unroll
      for (int r = 0; r < st; ++r) v0[r] = fmaxf(v0[r], v0[r + st]);
    float mt = fmaxf(v0[0], __shfl_xor(v0[0], 32, 64));
    float mn = fmaxf(m, mt);
    float corr = exp2f(m - mn);
    m = mn;
    float s0[16];
    #pragma unroll
    for (int r = 0; r < 16; ++r){
      float p0 = exp2f(sacc[0][r] - mn); sacc[0][r] = p0;
      float p1 = exp2f(sacc[1][r] - mn); sacc[1][r] = p1;
      s0[r] = p0 + p1;
    }
    #pragma unroll
    for (int st = 8; st >= 1; st >>= 1)
      #pragma unroll
      for (int r = 0; r < st; ++r) s0[r] += s0[r + st];
    float ps = s0[0] + __shfl_xor(s0[0], 32, 64);
    lsum = lsum * corr + ps;
    #pragma unroll
    for (int db = 0; db < 2; ++db)
      #pragma unroll
      for (int r = 0; r < 16; ++r) accO[db][r] *= corr;

    // ---- P (D-layout) -> P^T B-frags, in-register
    u32x4 W[4];
    #pragma unroll
    for (int kb2 = 0; kb2 < 2; ++kb2)
      #pragma unroll
      for (int sl = 0; sl < 2; ++sl){
        int bse = sl * 8;
        uint32_t a0 = cvtpk(sacc[kb2][bse + 0], sacc[kb2][bse + 1]);
        uint32_t a1 = cvtpk(sacc[kb2][bse + 2], sacc[kb2][bse + 3]);
        uint32_t b0 = cvtpk(sacc[kb2][bse + 4], sacc[kb2][bse + 5]);
        uint32_t b1 = cvtpk(sacc[kb2][bse + 6], sacc[kb2][bse + 7]);
        uint32_t xb0 = __shfl_xor(b0, 32, 64);
        uint32_t xb1 = __shfl_xor(b1, 32, 64);
        uint32_t xa0 = __shfl_xor(a0, 32, 64);
        uint32_t xa1 = __shfl_xor(a1, 32, 64);
        int ks = kb2 * 2 + sl;
        W[ks][0] = hi ? xb0 : a0;
        W[ks][1] = hi ? xb1 : a1;
        W[ks][2] = hi ? b0  : xa0;
        W[ks][3] = hi ? b1  : xa1;
      }

    // ---- O^T += V^T P^T
    __builtin_amdgcn_s_setprio(1);
    #pragma unroll
    for (int db = 0; db < 2; ++db){
      int row = db * 32 + ln;
      int sw = (row & 7) << 4;
      #pragma unroll
      for (int ks = 0; ks < 4; ++ks){
        short8 vf = *reinterpret_cast<const short8*>(Vc + row * 128 + ((ks * 32 + hi * 16) ^ sw));
        accO[db] = __builtin_amdgcn_mfma_f32_32x32x16_bf16(vf, __builtin_bit_cast(short8, W[ks]), accO[db], 0, 0, 0);
      }
    }
    __builtin_amdgcn_s_setprio(0);

    // ---- stage tile t+1 regs -> other buffer; issue loads for t+2
    if (t + 1 < 32){
      char* Kn = (char*)&KV[(t + 1) & 1][0][0];
      char* Vn = (char*)&KV[(t + 1) & 1][1][0];
      *reinterpret_cast<short8*>(Kn + sd0) = kst0;
      *reinterpret_cast<short8*>(Kn + sd1) = kst1;
      *reinterpret_cast<short8*>(Vn + sd0) = vst0;
      *reinterpret_cast<short8*>(Vn + sd1) = vst1;
    }
    if (t + 2 < 32){
      size_t j0 = (size_t)(t + 2) * 64;
      kst0 = *reinterpret_cast<const short8*>(kp + j0 * Dn + ko0);
      kst1 = *reinterpret_cast<const short8*>(kp + j0 * Dn + ko1);
      vst0 = *reinterpret_cast<const short8*>(vp + j0 + vo0);
      vst1 = *reinterpret_cast<const short8*>(vp + j0 + vo1);
    }
    __syncthreads();
  }

  // ---- epilogue: O^T[d][q] / lsum -> y[(b,l,512)]
  float inv = 1.0f / lsum;
  #pragma unroll
  for (int db = 0; db < 2; ++db)
    #pragma unroll
    for (int rq = 0; rq < 4; ++rq){
      uint32_t w0 = cvtpk(accO[db][rq * 4 + 0] * inv, accO[db][rq * 4 + 1] * inv);
      uint32_t w1 = cvtpk(accO[db][rq * 4 + 2] * inv, accO[db][rq * 4 + 3] * inv);
      int dd = db * 32 + rq * 8 + hi * 4;
      uint32_t* dst = reinterpret_cast<uint32_t*>(yp + (size_t)q * HIDn + dd);
      dst[0] = w0; dst[1] = w1;
    }
}

// ---------------- out GEMM (M=256 full) + bias + fused RMSNorm + g2 ----------------
__global__ __launch_bounds__(256) void k_out(const unsigned short* __restrict__ yb,
                                             const unsigned short* __restrict__ w,
                                             const float* __restrict__ bias,
                                             const float* __restrict__ g2,
                                             float* __restrict__ out){
  int b  = blockIdx.y;
  int l0 = blockIdx.x * 32;
  int wv = threadIdx.x >> 6, lane = threadIdx.x & 63;
  int grp = lane >> 4, lc = lane & 15;
  int mw = wv * 64;
  f32x4 acc[4][2] = {};
  const unsigned short* ybp = yb + (size_t)b * Ln * HIDn + (size_t)l0 * HIDn;
  for (int k0 = 0; k0 < HIDn; k0 += 32){
    int kc = k0 + grp * 8;
    short8 afr[4], bfr[2];
    #pragma unroll
    for (int mt = 0; mt < 4; ++mt)
      afr[mt] = *reinterpret_cast<const short8*>(w + (size_t)(mw + mt * 16 + lc) * HIDn + kc);
    #pragma unroll
    for (int nt = 0; nt < 2; ++nt)
      bfr[nt] = *reinterpret_cast<const short8*>(ybp + (size_t)(nt * 16 + lc) * HIDn + kc);
    #pragma unroll
    for (int mt = 0; mt < 4; ++mt)
      #pragma unroll
      for (int nt = 0; nt < 2; ++nt)
        acc[mt][nt] = __builtin_amdgcn_mfma_f32_16x16x32_bf16(afr[mt], bfr[nt], acc[mt][nt], 0, 0, 0);
  }
  __shared__ float cs[4][32];
  __shared__ float sc2[32];
  float part[2] = {0.f, 0.f};
  #pragma unroll
  for (int mt = 0; mt < 4; ++mt)
    #pragma unroll
    for (int nt = 0; nt < 2; ++nt)
      #pragma unroll
      for (int r = 0; r < 4; ++r){
        int o = mw + mt * 16 + grp * 4 + r;
        float v = acc[mt][nt][r] + bias[o];
        acc[mt][nt][r] = v;
        part[nt] += v * v;
      }
  #pragma unroll
  for (int nt = 0; nt < 2; ++nt)
    #pragma unroll
    for (int sh = 16; sh < 64; sh <<= 1) part[nt] += __shfl_xor(part[nt], sh, 64);
  if (lane < 16){ cs[wv][lc] = part[0]; cs[wv][16 + lc] = part[1]; }
  __syncthreads();
  if (threadIdx.x < 32){
    float t = cs[0][threadIdx.x] + cs[1][threadIdx.x] + cs[2][threadIdx.x] + cs[3][threadIdx.x];
    sc2[threadIdx.x] = 16.0f / fmaxf(sqrtf(t), 1e-12f);
  }
  __syncthreads();
  #pragma unroll
  for (int nt = 0; nt < 2; ++nt){
    float s2 = sc2[nt * 16 + lc];
    #pragma unroll
    for (int mt = 0; mt < 4; ++mt)
      #pragma unroll
      for (int r = 0; r < 4; ++r){
        int o = mw + mt * 16 + grp * 4 + r;
        int l = l0 + nt * 16 + lc;
        out[((size_t)(b * Cn + o)) * Ln + l] = acc[mt][nt][r] * s2 * g2[o];
      }
  }
}

// ---------------- launch ----------------
extern "C" void kernel_launch(void* const* d_in, const int* in_sizes, int n_in,
                              void* d_out, int out_size, void* d_ws, size_t ws_size,
                              hipStream_t stream){
  const float* x     = (const float*)d_in[0];
  const float* g1    = (const float*)d_in[1];
  const float* w_qkv = (const float*)d_in[2];
  const float* w_out = (const float*)d_in[3];
  const float* b_out = (const float*)d_in[4];
  const float* g2    = (const float*)d_in[5];

  char* wsb = (char*)d_ws;
  unsigned short* wqkv_b = (unsigned short*)(wsb + 0);
  unsigned short* wout_b = (unsigned short*)(wsb + 786432);
  float*          sbuf   = (float*)        (wsb + 1048576);
  unsigned short* xT     = (unsigned short*)(wsb + 1081344);
  unsigned short* qbuf   = (unsigned short*)(wsb + 5275648);
  unsigned short* kbuf   = (unsigned short*)(wsb + 13664256);
  unsigned short* vbuf   = (unsigned short*)(wsb + 22052864);
  unsigned short* ybuf   = (unsigned short*)(wsb + 30441472);

  k_cvt<<<384, 256, 0, stream>>>(w_qkv, wqkv_b, 1536 * 256);
  k_cvt<<<128, 256, 0, stream>>>(w_out, wout_b, 256 * 512);
  k_colnorm<<<128, 256, 0, stream>>>(x, sbuf);
  k_xt<<<dim3(32, 4, 4), 256, 0, stream>>>(x, sbuf, g1, xT);
  k_gemm_qk<<<dim3(16, 16, 4), 256, 0, stream>>>(xT, wqkv_b, qbuf, kbuf);
  k_gemm_v<<<dim3(16, 8, 4), 256, 0, stream>>>(xT, wqkv_b, vbuf);
  k_attn<<<512, 256, 0, stream>>>(qbuf, kbuf, vbuf, ybuf);
  k_out<<<dim3(64, 4), 256, 0, stream>>>(ybuf, wout_b, b_out, g2, (float*)d_out);
}